// Round 7
// baseline (110.654 us; speedup 1.0000x reference)
//
#include <hip/hip_runtime.h>
#include <math.h>
#include <stdint.h>

// out[b,c,h,w] = tanh(weight[idx,c] * img[b,c,h,w] + bias[idx,c])
// idx = (int32)(q0*65536 + q1*256 + q2), q_c = (img_c + 1)*127.5  (exact fp32, no fma)
//
// R7 design (structure from R6, micro-optimized). Evidence ledger:
//   R2: 4x MLP -> 0 BW change      => divergent gather throughput-capped ~3 TB/s.
//   R3/R4/R5: gather pass ~95-105us for 67/96/134 MB tables => cap is invariant
//             to table size/L3 residency; >=1 random line per pixel ~90us floor.
//   R6: uniformity-check + broadcast apply = 61.8us total (zero gathers).
// R7: -1 dispatch (memset node instead of 1-thread init kernel), check pass at
//     96 B/table/thread with nt dwordx4 loads (was 48), zero tail threads.
// Floor: 201 MB check read + 100 MB apply r/w ~= 44-46us at streaming BW.

#define HW_   (512 * 512)
#define CHW_  (3 * HW_)
#define PPT   8
#define GROUPS_PER_IMG (HW_ / PPT)
#define N_GROUPS (16 * GROUPS_PER_IMG)

#define IDX_MIN 8388607                  // min reachable idx for img in [0,1)
#define IDX_MAX 16777214                 // max reachable idx
#define CHK_BASE 8388600                 // %8==0 -> 8 rows/thread, no tail; floats %4==0
#define CHK_ROWS (16777216 - CHK_BASE)   // 8,388,616 rows (superset of reachable range)
#define CHK_T (CHK_ROWS / 8)             // 1,048,577 threads, 8 rows (24 floats)/table each

typedef float f4 __attribute__((ext_vector_type(4)));

// ---------------- Pass 1: streaming uniformity check ----------------
// Compares every row in [CHK_BASE, 16777215] against row IDX_MIN, both tables.
// 8 rows = 24 floats = 6 aligned dwordx4 nt-loads per table per thread.
__global__ __launch_bounds__(256) void
check_uniform_kernel(const float* __restrict__ weight,
                     const float* __restrict__ bias,
                     uint32_t* __restrict__ flag) {
    size_t t = (size_t)blockIdx.x * 256 + threadIdx.x;
    if (t >= CHK_T) return;

    const size_t r0 = (size_t)IDX_MIN * 3;
    const float wr[3] = {weight[r0], weight[r0 + 1], weight[r0 + 2]};
    const float br[3] = {bias[r0],   bias[r0 + 1],   bias[r0 + 2]};

    size_t f0 = (size_t)CHK_BASE * 3 + t * 24;   // 24 floats/table, %3==0 -> fixed phase
    const f4* pw = (const f4*)(weight + f0);
    const f4* pb = (const f4*)(bias + f0);

    bool mm = false;
#pragma unroll
    for (int k = 0; k < 6; ++k) {
        f4 a = __builtin_nontemporal_load(pw + k);
        f4 c = __builtin_nontemporal_load(pb + k);
        mm |= (a.x != wr[(4 * k + 0) % 3]) | (a.y != wr[(4 * k + 1) % 3]) |
              (a.z != wr[(4 * k + 2) % 3]) | (a.w != wr[(4 * k + 3) % 3]);
        mm |= (c.x != br[(4 * k + 0) % 3]) | (c.y != br[(4 * k + 1) % 3]) |
              (c.z != br[(4 * k + 2) % 3]) | (c.w != br[(4 * k + 3) % 3]);
    }

    if (__any(mm) && (threadIdx.x & 63) == 0)   // one atomic per wave, only on mismatch
        atomicOr(flag, 1u);
}

// ---------------- Pass 2: apply ----------------
// flag==0 (uniform LUT): pure streaming tanh(w*x+b), zero gathers.
// flag!=0: direct 2-table gather per pixel (always correct, R2 structure).
// Either way, per-pixel out-of-verified-range idx falls back to a direct gather.
__global__ __launch_bounds__(256) void
apply_kernel(const float* __restrict__ img,
             const float* __restrict__ weight,
             const float* __restrict__ bias,
             const uint32_t* __restrict__ flag,
             float* __restrict__ out) {
    int t = blockIdx.x * blockDim.x + threadIdx.x;
    if (t >= N_GROUPS) return;

    int b = t >> 15;
    int p = (t & (GROUPS_PER_IMG - 1)) << 3;

    const float* base = img + (size_t)b * CHW_ + p;
    f4 r0 = __builtin_nontemporal_load((const f4*)(base));
    f4 r1 = __builtin_nontemporal_load((const f4*)(base + 4));
    f4 g0 = __builtin_nontemporal_load((const f4*)(base + HW_));
    f4 g1 = __builtin_nontemporal_load((const f4*)(base + HW_ + 4));
    f4 c0 = __builtin_nontemporal_load((const f4*)(base + 2 * HW_));
    f4 c1 = __builtin_nontemporal_load((const f4*)(base + 2 * HW_ + 4));

    float xr[PPT] = {r0.x, r0.y, r0.z, r0.w, r1.x, r1.y, r1.z, r1.w};
    float xg[PPT] = {g0.x, g0.y, g0.z, g0.w, g1.x, g1.y, g1.z, g1.w};
    float xb[PPT] = {c0.x, c0.y, c0.z, c0.w, c1.x, c1.y, c1.z, c1.w};

    // Exact-fp32 index math (bit-matches numpy; never fma-contracted)
    int idx[PPT];
#pragma unroll
    for (int i = 0; i < PPT; ++i) {
        float q0 = __fmul_rn(__fadd_rn(xr[i], 1.0f), 127.5f);
        float q1 = __fmul_rn(__fadd_rn(xg[i], 1.0f), 127.5f);
        float q2 = __fmul_rn(__fadd_rn(xb[i], 1.0f), 127.5f);
        float s  = __fadd_rn(__fadd_rn(__fmul_rn(q0, 65536.0f),
                                       __fmul_rn(q1, 256.0f)),
                             q2);
        idx[i] = (int)s;
    }

    float wv[PPT][3], bv[PPT][3];
    bool uni = (flag[0] == 0u);   // grid-uniform scalar branch

    if (uni) {
        const size_t rr = (size_t)IDX_MIN * 3;
        float uw0 = weight[rr], uw1 = weight[rr + 1], uw2 = weight[rr + 2];
        float ub0 = bias[rr],   ub1 = bias[rr + 1],   ub2 = bias[rr + 2];
#pragma unroll
        for (int i = 0; i < PPT; ++i) {
            wv[i][0] = uw0; wv[i][1] = uw1; wv[i][2] = uw2;
            bv[i][0] = ub0; bv[i][1] = ub1; bv[i][2] = ub2;
        }
        // Safety: idx outside the verified range -> direct gather (never taken
        // for img in [0,1); wave-uniformly false -> s_cbranch_execz skips)
#pragma unroll
        for (int i = 0; i < PPT; ++i) {
            if ((unsigned)(idx[i] - IDX_MIN) > (unsigned)(IDX_MAX - IDX_MIN)) {
                const float* wp = weight + (size_t)idx[i] * 3;
                const float* bp = bias   + (size_t)idx[i] * 3;
                wv[i][0] = wp[0]; wv[i][1] = wp[1]; wv[i][2] = wp[2];
                bv[i][0] = bp[0]; bv[i][1] = bp[1]; bv[i][2] = bp[2];
            }
        }
    } else {
        // Non-uniform LUT: direct 2-table gather per pixel (correct, slower)
#pragma unroll
        for (int i = 0; i < PPT; ++i) {
            const float* wp = weight + (size_t)idx[i] * 3;
            wv[i][0] = wp[0]; wv[i][1] = wp[1]; wv[i][2] = wp[2];
        }
#pragma unroll
        for (int i = 0; i < PPT; ++i) {
            const float* bp = bias + (size_t)idx[i] * 3;
            bv[i][0] = bp[0]; bv[i][1] = bp[1]; bv[i][2] = bp[2];
        }
    }

    float orr[PPT], org[PPT], orb[PPT];
#pragma unroll
    for (int i = 0; i < PPT; ++i) {
        orr[i] = tanhf(fmaf(wv[i][0], xr[i], bv[i][0]));
        org[i] = tanhf(fmaf(wv[i][1], xg[i], bv[i][1]));
        orb[i] = tanhf(fmaf(wv[i][2], xb[i], bv[i][2]));
    }

    float* obase = out + (size_t)b * CHW_ + p;
    f4 v;
    v = (f4){orr[0], orr[1], orr[2], orr[3]}; __builtin_nontemporal_store(v, (f4*)(obase));
    v = (f4){orr[4], orr[5], orr[6], orr[7]}; __builtin_nontemporal_store(v, (f4*)(obase + 4));
    v = (f4){org[0], org[1], org[2], org[3]}; __builtin_nontemporal_store(v, (f4*)(obase + HW_));
    v = (f4){org[4], org[5], org[6], org[7]}; __builtin_nontemporal_store(v, (f4*)(obase + HW_ + 4));
    v = (f4){orb[0], orb[1], orb[2], orb[3]}; __builtin_nontemporal_store(v, (f4*)(obase + 2 * HW_));
    v = (f4){orb[4], orb[5], orb[6], orb[7]}; __builtin_nontemporal_store(v, (f4*)(obase + 2 * HW_ + 4));
}

// ---------------- Fallback if ws is too small: direct gather only ----------------
__global__ __launch_bounds__(256) void
lut_affine_tanh_direct(const float* __restrict__ img,
                       const float* __restrict__ weight,
                       const float* __restrict__ bias,
                       float* __restrict__ out) {
    int t = blockIdx.x * blockDim.x + threadIdx.x;
    if (t >= N_GROUPS) return;
    int b = t >> 15;
    int p = (t & (GROUPS_PER_IMG - 1)) << 3;
    const float* base = img + (size_t)b * CHW_ + p;
    float4 r0 = *(const float4*)(base);
    float4 r1 = *(const float4*)(base + 4);
    float4 g0 = *(const float4*)(base + HW_);
    float4 g1 = *(const float4*)(base + HW_ + 4);
    float4 c0 = *(const float4*)(base + 2 * HW_);
    float4 c1 = *(const float4*)(base + 2 * HW_ + 4);
    float xr[PPT] = {r0.x, r0.y, r0.z, r0.w, r1.x, r1.y, r1.z, r1.w};
    float xg[PPT] = {g0.x, g0.y, g0.z, g0.w, g1.x, g1.y, g1.z, g1.w};
    float xb[PPT] = {c0.x, c0.y, c0.z, c0.w, c1.x, c1.y, c1.z, c1.w};
    int idx[PPT];
#pragma unroll
    for (int i = 0; i < PPT; ++i) {
        float q0 = __fmul_rn(__fadd_rn(xr[i], 1.0f), 127.5f);
        float q1 = __fmul_rn(__fadd_rn(xg[i], 1.0f), 127.5f);
        float q2 = __fmul_rn(__fadd_rn(xb[i], 1.0f), 127.5f);
        float s  = __fadd_rn(__fadd_rn(__fmul_rn(q0, 65536.0f),
                                       __fmul_rn(q1, 256.0f)), q2);
        idx[i] = (int)s;
    }
    float wv[PPT][3], bv[PPT][3];
#pragma unroll
    for (int i = 0; i < PPT; ++i) {
        const float* wp = weight + (size_t)idx[i] * 3;
        wv[i][0] = wp[0]; wv[i][1] = wp[1]; wv[i][2] = wp[2];
    }
#pragma unroll
    for (int i = 0; i < PPT; ++i) {
        const float* bp = bias + (size_t)idx[i] * 3;
        bv[i][0] = bp[0]; bv[i][1] = bp[1]; bv[i][2] = bp[2];
    }
    float orr[PPT], org[PPT], orb[PPT];
#pragma unroll
    for (int i = 0; i < PPT; ++i) {
        orr[i] = tanhf(fmaf(wv[i][0], xr[i], bv[i][0]));
        org[i] = tanhf(fmaf(wv[i][1], xg[i], bv[i][1]));
        orb[i] = tanhf(fmaf(wv[i][2], xb[i], bv[i][2]));
    }
    float* obase = out + (size_t)b * CHW_ + p;
    *(float4*)(obase)               = make_float4(orr[0], orr[1], orr[2], orr[3]);
    *(float4*)(obase + 4)           = make_float4(orr[4], orr[5], orr[6], orr[7]);
    *(float4*)(obase + HW_)         = make_float4(org[0], org[1], org[2], org[3]);
    *(float4*)(obase + HW_ + 4)     = make_float4(org[4], org[5], org[6], org[7]);
    *(float4*)(obase + 2 * HW_)     = make_float4(orb[0], orb[1], orb[2], orb[3]);
    *(float4*)(obase + 2 * HW_ + 4) = make_float4(orb[4], orb[5], orb[6], orb[7]);
}

extern "C" void kernel_launch(void* const* d_in, const int* in_sizes, int n_in,
                              void* d_out, int out_size, void* d_ws, size_t ws_size,
                              hipStream_t stream) {
    const float* img    = (const float*)d_in[0];
    const float* weight = (const float*)d_in[1];
    const float* bias   = (const float*)d_in[2];
    float* out = (float*)d_out;

    if (ws_size >= sizeof(uint32_t)) {
        uint32_t* flag = (uint32_t*)d_ws;
        // memset node (graph-capture legal; the harness itself uses hipMemsetAsync)
        hipMemsetAsync(flag, 0, sizeof(uint32_t), stream);
        check_uniform_kernel<<<(int)((CHK_T + 255) / 256), 256, 0, stream>>>(weight, bias, flag);
        apply_kernel<<<N_GROUPS / 256, 256, 0, stream>>>(img, weight, bias, flag, out);
    } else {
        lut_affine_tanh_direct<<<N_GROUPS / 256, 256, 0, stream>>>(img, weight, bias, out);
    }
}

// Round 8
// 63.338 us; speedup vs baseline: 1.7471x; 1.7471x over previous
//
#include <hip/hip_runtime.h>
#include <math.h>
#include <stdint.h>

// out[b,c,h,w] = tanh(weight[idx,c] * img[b,c,h,w] + bias[idx,c])
// idx = (int32)(q0*65536 + q1*256 + q2), q_c = (img_c + 1)*127.5  (exact fp32, no fma)
//
// R8 design. Evidence ledger:
//   R2: 4x MLP -> 0 BW change   => divergent gather throughput-capped ~3 TB/s, invariant.
//   R3-R5: >=1 random line per pixel has a ~90us floor regardless of table size.
//   R6: uniformity-check + broadcast apply (serial, 3 dispatches) = 61.8us. PROVEN.
//   R7: nt loads on 96B-strided check + memset node = 110.7us REGRESSION -> both reverted.
// R8: with a fixup pass, apply doesn't need the flag -> check and apply are
// independent -> fuse into ONE megakernel (8193 check blocks + 2048 apply blocks,
// interleaved 4:1). Fixup early-exits on flag==0 (uniform). Serial 35+16us becomes
// one ~44us memory-bound pass: 251 MB read + 50 MB write.
//   check part: R6's proven 4-rows/thread plain f4 loads (do NOT use nt on strided
//   patterns — R7 lesson; nt only on fully-contiguous apply streams).

#define HW_   (512 * 512)
#define CHW_  (3 * HW_)
#define PPT   8
#define GROUPS_PER_IMG (HW_ / PPT)
#define N_GROUPS (16 * GROUPS_PER_IMG)

#define IDX_MIN 8388607                  // min reachable idx for img in [0,1)
#define IDX_MAX 16777214                 // max reachable idx
#define CHK_BASE 8388604                 // %4==0 -> float offset %4==0 -> 16B-aligned
#define CHK_ROWS (16777216 - CHK_BASE)   // 8,388,612 rows (superset of reachable)
#define CHK_T (CHK_ROWS / 4)             // 2,097,153 threads, 4 rows (12 floats)/table
#define CHK_BLOCKS ((CHK_T + 255) / 256)         // 8193
#define APPLY_BLOCKS (N_GROUPS / 256)            // 2048
#define TOTAL_BLOCKS (CHK_BLOCKS + APPLY_BLOCKS) // 10241

typedef float f4 __attribute__((ext_vector_type(4)));

// ---------------- Pass 0: reset the uniformity flag ----------------
__global__ void flag_init_kernel(uint32_t* flag) { flag[0] = 0u; }

// ---------------- Pass 1: fused check + broadcast-apply megakernel ----------------
__global__ __launch_bounds__(256) void
mega_kernel(const float* __restrict__ img,
            const float* __restrict__ weight,
            const float* __restrict__ bias,
            uint32_t* __restrict__ flag,
            float* __restrict__ out) {
    int blk = blockIdx.x;
    int grp = blk / 5;
    int rem = blk - 5 * grp;
    bool is_apply = (rem == 4) && (grp < APPLY_BLOCKS);

    if (is_apply) {
        // ---- apply block: broadcast w/b, streaming tanh ----
        int t = grp * 256 + threadIdx.x;          // t < N_GROUPS always
        int b = t >> 15;
        int p = (t & (GROUPS_PER_IMG - 1)) << 3;

        const float* base = img + (size_t)b * CHW_ + p;
        f4 r0 = __builtin_nontemporal_load((const f4*)(base));
        f4 r1 = __builtin_nontemporal_load((const f4*)(base + 4));
        f4 g0 = __builtin_nontemporal_load((const f4*)(base + HW_));
        f4 g1 = __builtin_nontemporal_load((const f4*)(base + HW_ + 4));
        f4 c0 = __builtin_nontemporal_load((const f4*)(base + 2 * HW_));
        f4 c1 = __builtin_nontemporal_load((const f4*)(base + 2 * HW_ + 4));

        float xr[PPT] = {r0.x, r0.y, r0.z, r0.w, r1.x, r1.y, r1.z, r1.w};
        float xg[PPT] = {g0.x, g0.y, g0.z, g0.w, g1.x, g1.y, g1.z, g1.w};
        float xb[PPT] = {c0.x, c0.y, c0.z, c0.w, c1.x, c1.y, c1.z, c1.w};

        // Exact-fp32 index math (bit-matches numpy; never fma-contracted)
        int idx[PPT];
#pragma unroll
        for (int i = 0; i < PPT; ++i) {
            float q0 = __fmul_rn(__fadd_rn(xr[i], 1.0f), 127.5f);
            float q1 = __fmul_rn(__fadd_rn(xg[i], 1.0f), 127.5f);
            float q2 = __fmul_rn(__fadd_rn(xb[i], 1.0f), 127.5f);
            float s  = __fadd_rn(__fadd_rn(__fmul_rn(q0, 65536.0f),
                                           __fmul_rn(q1, 256.0f)),
                                 q2);
            idx[i] = (int)s;
        }

        const size_t rr = (size_t)IDX_MIN * 3;    // uniform scalar loads
        float uw0 = weight[rr], uw1 = weight[rr + 1], uw2 = weight[rr + 2];
        float ub0 = bias[rr],   ub1 = bias[rr + 1],   ub2 = bias[rr + 2];

        float wv[PPT][3], bv[PPT][3];
#pragma unroll
        for (int i = 0; i < PPT; ++i) {
            wv[i][0] = uw0; wv[i][1] = uw1; wv[i][2] = uw2;
            bv[i][0] = ub0; bv[i][1] = ub1; bv[i][2] = ub2;
        }
        // Safety: idx outside the verified range -> direct gather (never taken
        // for img in [0,1); wave-uniformly false -> s_cbranch_execz skips)
#pragma unroll
        for (int i = 0; i < PPT; ++i) {
            if ((unsigned)(idx[i] - IDX_MIN) > (unsigned)(IDX_MAX - IDX_MIN)) {
                const float* wp = weight + (size_t)idx[i] * 3;
                const float* bp = bias   + (size_t)idx[i] * 3;
                wv[i][0] = wp[0]; wv[i][1] = wp[1]; wv[i][2] = wp[2];
                bv[i][0] = bp[0]; bv[i][1] = bp[1]; bv[i][2] = bp[2];
            }
        }

        float orr[PPT], org[PPT], orb[PPT];
#pragma unroll
        for (int i = 0; i < PPT; ++i) {
            orr[i] = tanhf(fmaf(wv[i][0], xr[i], bv[i][0]));
            org[i] = tanhf(fmaf(wv[i][1], xg[i], bv[i][1]));
            orb[i] = tanhf(fmaf(wv[i][2], xb[i], bv[i][2]));
        }

        float* obase = out + (size_t)b * CHW_ + p;
        f4 v;
        v = (f4){orr[0], orr[1], orr[2], orr[3]}; __builtin_nontemporal_store(v, (f4*)(obase));
        v = (f4){orr[4], orr[5], orr[6], orr[7]}; __builtin_nontemporal_store(v, (f4*)(obase + 4));
        v = (f4){org[0], org[1], org[2], org[3]}; __builtin_nontemporal_store(v, (f4*)(obase + HW_));
        v = (f4){org[4], org[5], org[6], org[7]}; __builtin_nontemporal_store(v, (f4*)(obase + HW_ + 4));
        v = (f4){orb[0], orb[1], orb[2], orb[3]}; __builtin_nontemporal_store(v, (f4*)(obase + 2 * HW_));
        v = (f4){orb[4], orb[5], orb[6], orb[7]}; __builtin_nontemporal_store(v, (f4*)(obase + 2 * HW_ + 4));
    } else {
        // ---- check block: R6's proven uniformity scan (plain loads) ----
        int check_id = blk - min((blk + 1) / 5, (int)APPLY_BLOCKS);
        size_t t = (size_t)check_id * 256 + threadIdx.x;
        if (t >= CHK_T) return;

        const size_t r0 = (size_t)IDX_MIN * 3;
        const float w0 = weight[r0], w1 = weight[r0 + 1], w2 = weight[r0 + 2];
        const float b0 = bias[r0],   b1 = bias[r0 + 1],   b2 = bias[r0 + 2];

        size_t f0 = (size_t)CHK_BASE * 3 + t * 12;  // %3==0 -> fixed component phase
        const f4* pw = (const f4*)(weight + f0);
        const f4* pb = (const f4*)(bias + f0);
        f4 a0 = pw[0], a1 = pw[1], a2 = pw[2];
        f4 c0 = pb[0], c1 = pb[1], c2 = pb[2];

        bool mm = false;
        mm |= (a0.x != w0) | (a0.y != w1) | (a0.z != w2) | (a0.w != w0);
        mm |= (a1.x != w1) | (a1.y != w2) | (a1.z != w0) | (a1.w != w1);
        mm |= (a2.x != w2) | (a2.y != w0) | (a2.z != w1) | (a2.w != w2);
        mm |= (c0.x != b0) | (c0.y != b1) | (c0.z != b2) | (c0.w != b0);
        mm |= (c1.x != b1) | (c1.y != b2) | (c1.z != b0) | (c1.w != b1);
        mm |= (c2.x != b2) | (c2.y != b0) | (c2.z != b1) | (c2.w != b2);

        if (__any(mm) && (threadIdx.x & 63) == 0)   // one atomic per wave, mismatch only
            atomicOr(flag, 1u);
    }
}

// ---------------- Pass 2: fixup (no-op when LUT uniform) ----------------
// flag!=0: redo every pixel with the always-correct direct 2-table gather.
__global__ __launch_bounds__(256) void
fixup_kernel(const float* __restrict__ img,
             const float* __restrict__ weight,
             const float* __restrict__ bias,
             const uint32_t* __restrict__ flag,
             float* __restrict__ out) {
    if (flag[0] == 0u) return;   // uniform LUT: broadcast result already correct

    int t = blockIdx.x * blockDim.x + threadIdx.x;
    if (t >= N_GROUPS) return;
    int b = t >> 15;
    int p = (t & (GROUPS_PER_IMG - 1)) << 3;
    const float* base = img + (size_t)b * CHW_ + p;
    float4 r0 = *(const float4*)(base);
    float4 r1 = *(const float4*)(base + 4);
    float4 g0 = *(const float4*)(base + HW_);
    float4 g1 = *(const float4*)(base + HW_ + 4);
    float4 c0 = *(const float4*)(base + 2 * HW_);
    float4 c1 = *(const float4*)(base + 2 * HW_ + 4);
    float xr[PPT] = {r0.x, r0.y, r0.z, r0.w, r1.x, r1.y, r1.z, r1.w};
    float xg[PPT] = {g0.x, g0.y, g0.z, g0.w, g1.x, g1.y, g1.z, g1.w};
    float xb[PPT] = {c0.x, c0.y, c0.z, c0.w, c1.x, c1.y, c1.z, c1.w};
    int idx[PPT];
#pragma unroll
    for (int i = 0; i < PPT; ++i) {
        float q0 = __fmul_rn(__fadd_rn(xr[i], 1.0f), 127.5f);
        float q1 = __fmul_rn(__fadd_rn(xg[i], 1.0f), 127.5f);
        float q2 = __fmul_rn(__fadd_rn(xb[i], 1.0f), 127.5f);
        float s  = __fadd_rn(__fadd_rn(__fmul_rn(q0, 65536.0f),
                                       __fmul_rn(q1, 256.0f)), q2);
        idx[i] = (int)s;
    }
    float wv[PPT][3], bv[PPT][3];
#pragma unroll
    for (int i = 0; i < PPT; ++i) {
        const float* wp = weight + (size_t)idx[i] * 3;
        wv[i][0] = wp[0]; wv[i][1] = wp[1]; wv[i][2] = wp[2];
    }
#pragma unroll
    for (int i = 0; i < PPT; ++i) {
        const float* bp = bias + (size_t)idx[i] * 3;
        bv[i][0] = bp[0]; bv[i][1] = bp[1]; bv[i][2] = bp[2];
    }
    float orr[PPT], org[PPT], orb[PPT];
#pragma unroll
    for (int i = 0; i < PPT; ++i) {
        orr[i] = tanhf(fmaf(wv[i][0], xr[i], bv[i][0]));
        org[i] = tanhf(fmaf(wv[i][1], xg[i], bv[i][1]));
        orb[i] = tanhf(fmaf(wv[i][2], xb[i], bv[i][2]));
    }
    float* obase = out + (size_t)b * CHW_ + p;
    *(float4*)(obase)               = make_float4(orr[0], orr[1], orr[2], orr[3]);
    *(float4*)(obase + 4)           = make_float4(orr[4], orr[5], orr[6], orr[7]);
    *(float4*)(obase + HW_)         = make_float4(org[0], org[1], org[2], org[3]);
    *(float4*)(obase + HW_ + 4)     = make_float4(org[4], org[5], org[6], org[7]);
    *(float4*)(obase + 2 * HW_)     = make_float4(orb[0], orb[1], orb[2], orb[3]);
    *(float4*)(obase + 2 * HW_ + 4) = make_float4(orb[4], orb[5], orb[6], orb[7]);
}

// ---------------- Fallback if ws is too small: direct gather only ----------------
__global__ __launch_bounds__(256) void
lut_affine_tanh_direct(const float* __restrict__ img,
                       const float* __restrict__ weight,
                       const float* __restrict__ bias,
                       float* __restrict__ out) {
    int t = blockIdx.x * blockDim.x + threadIdx.x;
    if (t >= N_GROUPS) return;
    int b = t >> 15;
    int p = (t & (GROUPS_PER_IMG - 1)) << 3;
    const float* base = img + (size_t)b * CHW_ + p;
    float4 r0 = *(const float4*)(base);
    float4 r1 = *(const float4*)(base + 4);
    float4 g0 = *(const float4*)(base + HW_);
    float4 g1 = *(const float4*)(base + HW_ + 4);
    float4 c0 = *(const float4*)(base + 2 * HW_);
    float4 c1 = *(const float4*)(base + 2 * HW_ + 4);
    float xr[PPT] = {r0.x, r0.y, r0.z, r0.w, r1.x, r1.y, r1.z, r1.w};
    float xg[PPT] = {g0.x, g0.y, g0.z, g0.w, g1.x, g1.y, g1.z, g1.w};
    float xb[PPT] = {c0.x, c0.y, c0.z, c0.w, c1.x, c1.y, c1.z, c1.w};
    int idx[PPT];
#pragma unroll
    for (int i = 0; i < PPT; ++i) {
        float q0 = __fmul_rn(__fadd_rn(xr[i], 1.0f), 127.5f);
        float q1 = __fmul_rn(__fadd_rn(xg[i], 1.0f), 127.5f);
        float q2 = __fmul_rn(__fadd_rn(xb[i], 1.0f), 127.5f);
        float s  = __fadd_rn(__fadd_rn(__fmul_rn(q0, 65536.0f),
                                       __fmul_rn(q1, 256.0f)), q2);
        idx[i] = (int)s;
    }
    float wv[PPT][3], bv[PPT][3];
#pragma unroll
    for (int i = 0; i < PPT; ++i) {
        const float* wp = weight + (size_t)idx[i] * 3;
        wv[i][0] = wp[0]; wv[i][1] = wp[1]; wv[i][2] = wp[2];
    }
#pragma unroll
    for (int i = 0; i < PPT; ++i) {
        const float* bp = bias + (size_t)idx[i] * 3;
        bv[i][0] = bp[0]; bv[i][1] = bp[1]; bv[i][2] = bp[2];
    }
    float orr[PPT], org[PPT], orb[PPT];
#pragma unroll
    for (int i = 0; i < PPT; ++i) {
        orr[i] = tanhf(fmaf(wv[i][0], xr[i], bv[i][0]));
        org[i] = tanhf(fmaf(wv[i][1], xg[i], bv[i][1]));
        orb[i] = tanhf(fmaf(wv[i][2], xb[i], bv[i][2]));
    }
    float* obase = out + (size_t)b * CHW_ + p;
    *(float4*)(obase)               = make_float4(orr[0], orr[1], orr[2], orr[3]);
    *(float4*)(obase + 4)           = make_float4(orr[4], orr[5], orr[6], orr[7]);
    *(float4*)(obase + HW_)         = make_float4(org[0], org[1], org[2], org[3]);
    *(float4*)(obase + HW_ + 4)     = make_float4(org[4], org[5], org[6], org[7]);
    *(float4*)(obase + 2 * HW_)     = make_float4(orb[0], orb[1], orb[2], orb[3]);
    *(float4*)(obase + 2 * HW_ + 4) = make_float4(orb[4], orb[5], orb[6], orb[7]);
}

extern "C" void kernel_launch(void* const* d_in, const int* in_sizes, int n_in,
                              void* d_out, int out_size, void* d_ws, size_t ws_size,
                              hipStream_t stream) {
    const float* img    = (const float*)d_in[0];
    const float* weight = (const float*)d_in[1];
    const float* bias   = (const float*)d_in[2];
    float* out = (float*)d_out;

    if (ws_size >= sizeof(uint32_t)) {
        uint32_t* flag = (uint32_t*)d_ws;
        flag_init_kernel<<<1, 1, 0, stream>>>(flag);
        mega_kernel<<<TOTAL_BLOCKS, 256, 0, stream>>>(img, weight, bias, flag, out);
        fixup_kernel<<<APPLY_BLOCKS, 256, 0, stream>>>(img, weight, bias, flag, out);
    } else {
        lut_affine_tanh_direct<<<N_GROUPS / 256, 256, 0, stream>>>(img, weight, bias, out);
    }
}

// Round 9
// 63.164 us; speedup vs baseline: 1.7519x; 1.0028x over previous
//
#include <hip/hip_runtime.h>
#include <math.h>
#include <stdint.h>

// out[b,c,h,w] = tanh(weight[idx,c] * img[b,c,h,w] + bias[idx,c])
// idx = (int32)(q0*65536 + q1*256 + q2), q_c = (img_c + 1)*127.5  (exact fp32, no fma)
//
// R9 design. Evidence ledger:
//   R2: 4x MLP -> 0 BW change   => divergent gather throughput-capped ~3 TB/s, invariant.
//   R3-R5: >=1 random line per pixel has a ~90us floor regardless of table size.
//   R6: uniformity-check + broadcast apply (serial, 3 dispatches) = 61.8us. BEST.
//   R7: nt on 48B-lane-strided check = collapse (nt defeats the line merging that
//       pattern needs). R8: fusing check+apply = neutral (63.3) -> not dispatch-bound.
// R9 (one variable vs R6): the check scan was lane-strided 48B/lane -> one wave
// instruction touches 48 lines (3x the request rate of coalesced). Rewrite as a
// wave-coalesced grid-stride float4 loop; total threads % 3 == 0 makes each
// thread's row-component phase loop-invariant (expected vectors selected once,
// no runtime-indexed arrays).

#define HW_   (512 * 512)
#define CHW_  (3 * HW_)
#define PPT   8
#define GROUPS_PER_IMG (HW_ / PPT)
#define N_GROUPS (16 * GROUPS_PER_IMG)

#define IDX_MIN 8388607                    // min reachable idx for img in [0,1)
#define IDX_MAX 16777214                   // max reachable idx
#define CHK_BASE 8388604                   // rounded down so float base %4==0 (16B-aligned)
#define CHK_F0 ((size_t)CHK_BASE * 3)      // 25165812, %4==0
#define CHK_NV4 ((50331648UL - CHK_F0) / 4)  // 6,291,459 float4s per table
#define CHK_BLOCKS 1536
#define CHK_THREADS ((size_t)CHK_BLOCKS * 256)  // 393216, %3==0 -> fixed phase/thread

typedef float f4 __attribute__((ext_vector_type(4)));

// ---------------- Pass 0: reset the uniformity flag ----------------
__global__ void flag_init_kernel(uint32_t* flag) { flag[0] = 0u; }

// ---------------- Pass 1: wave-coalesced streaming uniformity check ----------------
// Verifies every row in [CHK_BASE, 16777215] equals row IDX_MIN, both tables.
// Lane i loads float4 at (t + k*CHK_THREADS): consecutive lanes -> consecutive
// 16B -> 1KB per wave instruction (16 lines). Phase t%3 is loop-invariant.
__global__ __launch_bounds__(256) void
check_uniform_kernel(const float* __restrict__ weight,
                     const float* __restrict__ bias,
                     uint32_t* __restrict__ flag) {
    size_t t = (size_t)blockIdx.x * 256 + threadIdx.x;
    int m = (int)(t % 3);

    const size_t r0 = (size_t)IDX_MIN * 3;
    float w0 = weight[r0], w1 = weight[r0 + 1], w2 = weight[r0 + 2];
    float b0 = bias[r0],   b1 = bias[r0 + 1],   b2 = bias[r0 + 2];

    // expected float4 for this thread's phase (component c has row-component (m+c)%3)
    f4 ew = (m == 0) ? (f4){w0, w1, w2, w0}
          : (m == 1) ? (f4){w1, w2, w0, w1}
                     : (f4){w2, w0, w1, w2};
    f4 eb = (m == 0) ? (f4){b0, b1, b2, b0}
          : (m == 1) ? (f4){b1, b2, b0, b1}
                     : (f4){b2, b0, b1, b2};

    const f4* pw = (const f4*)(weight + CHK_F0);
    const f4* pb = (const f4*)(bias + CHK_F0);

    bool mm = false;
    for (size_t i = t; i < CHK_NV4; i += CHK_THREADS) {
        f4 a = pw[i];
        f4 c = pb[i];
        mm |= (a.x != ew.x) | (a.y != ew.y) | (a.z != ew.z) | (a.w != ew.w);
        mm |= (c.x != eb.x) | (c.y != eb.y) | (c.z != eb.z) | (c.w != eb.w);
    }

    if (__any(mm) && (threadIdx.x & 63) == 0)   // one atomic per wave, mismatch only
        atomicOr(flag, 1u);
}

// ---------------- Pass 2: apply (R6-proven, unchanged) ----------------
// flag==0 (uniform LUT): pure streaming tanh(w*x+b), zero gathers.
// flag!=0: direct 2-table gather per pixel (always correct).
// Either way, per-pixel out-of-verified-range idx falls back to a direct gather.
__global__ __launch_bounds__(256) void
apply_kernel(const float* __restrict__ img,
             const float* __restrict__ weight,
             const float* __restrict__ bias,
             const uint32_t* __restrict__ flag,
             float* __restrict__ out) {
    int t = blockIdx.x * blockDim.x + threadIdx.x;
    if (t >= N_GROUPS) return;

    int b = t >> 15;
    int p = (t & (GROUPS_PER_IMG - 1)) << 3;

    const float* base = img + (size_t)b * CHW_ + p;
    f4 r0 = __builtin_nontemporal_load((const f4*)(base));
    f4 r1 = __builtin_nontemporal_load((const f4*)(base + 4));
    f4 g0 = __builtin_nontemporal_load((const f4*)(base + HW_));
    f4 g1 = __builtin_nontemporal_load((const f4*)(base + HW_ + 4));
    f4 c0 = __builtin_nontemporal_load((const f4*)(base + 2 * HW_));
    f4 c1 = __builtin_nontemporal_load((const f4*)(base + 2 * HW_ + 4));

    float xr[PPT] = {r0.x, r0.y, r0.z, r0.w, r1.x, r1.y, r1.z, r1.w};
    float xg[PPT] = {g0.x, g0.y, g0.z, g0.w, g1.x, g1.y, g1.z, g1.w};
    float xb[PPT] = {c0.x, c0.y, c0.z, c0.w, c1.x, c1.y, c1.z, c1.w};

    // Exact-fp32 index math (bit-matches numpy; never fma-contracted)
    int idx[PPT];
#pragma unroll
    for (int i = 0; i < PPT; ++i) {
        float q0 = __fmul_rn(__fadd_rn(xr[i], 1.0f), 127.5f);
        float q1 = __fmul_rn(__fadd_rn(xg[i], 1.0f), 127.5f);
        float q2 = __fmul_rn(__fadd_rn(xb[i], 1.0f), 127.5f);
        float s  = __fadd_rn(__fadd_rn(__fmul_rn(q0, 65536.0f),
                                       __fmul_rn(q1, 256.0f)),
                             q2);
        idx[i] = (int)s;
    }

    float wv[PPT][3], bv[PPT][3];
    bool uni = (flag[0] == 0u);   // grid-uniform scalar branch

    if (uni) {
        const size_t rr = (size_t)IDX_MIN * 3;
        float uw0 = weight[rr], uw1 = weight[rr + 1], uw2 = weight[rr + 2];
        float ub0 = bias[rr],   ub1 = bias[rr + 1],   ub2 = bias[rr + 2];
#pragma unroll
        for (int i = 0; i < PPT; ++i) {
            wv[i][0] = uw0; wv[i][1] = uw1; wv[i][2] = uw2;
            bv[i][0] = ub0; bv[i][1] = ub1; bv[i][2] = ub2;
        }
        // Safety: idx outside the verified range -> direct gather (never taken
        // for img in [0,1); wave-uniformly false -> s_cbranch_execz skips)
#pragma unroll
        for (int i = 0; i < PPT; ++i) {
            if ((unsigned)(idx[i] - IDX_MIN) > (unsigned)(IDX_MAX - IDX_MIN)) {
                const float* wp = weight + (size_t)idx[i] * 3;
                const float* bp = bias   + (size_t)idx[i] * 3;
                wv[i][0] = wp[0]; wv[i][1] = wp[1]; wv[i][2] = wp[2];
                bv[i][0] = bp[0]; bv[i][1] = bp[1]; bv[i][2] = bp[2];
            }
        }
    } else {
        // Non-uniform LUT: direct 2-table gather per pixel (correct, slower)
#pragma unroll
        for (int i = 0; i < PPT; ++i) {
            const float* wp = weight + (size_t)idx[i] * 3;
            wv[i][0] = wp[0]; wv[i][1] = wp[1]; wv[i][2] = wp[2];
        }
#pragma unroll
        for (int i = 0; i < PPT; ++i) {
            const float* bp = bias + (size_t)idx[i] * 3;
            bv[i][0] = bp[0]; bv[i][1] = bp[1]; bv[i][2] = bp[2];
        }
    }

    float orr[PPT], org[PPT], orb[PPT];
#pragma unroll
    for (int i = 0; i < PPT; ++i) {
        orr[i] = tanhf(fmaf(wv[i][0], xr[i], bv[i][0]));
        org[i] = tanhf(fmaf(wv[i][1], xg[i], bv[i][1]));
        orb[i] = tanhf(fmaf(wv[i][2], xb[i], bv[i][2]));
    }

    float* obase = out + (size_t)b * CHW_ + p;
    f4 v;
    v = (f4){orr[0], orr[1], orr[2], orr[3]}; __builtin_nontemporal_store(v, (f4*)(obase));
    v = (f4){orr[4], orr[5], orr[6], orr[7]}; __builtin_nontemporal_store(v, (f4*)(obase + 4));
    v = (f4){org[0], org[1], org[2], org[3]}; __builtin_nontemporal_store(v, (f4*)(obase + HW_));
    v = (f4){org[4], org[5], org[6], org[7]}; __builtin_nontemporal_store(v, (f4*)(obase + HW_ + 4));
    v = (f4){orb[0], orb[1], orb[2], orb[3]}; __builtin_nontemporal_store(v, (f4*)(obase + 2 * HW_));
    v = (f4){orb[4], orb[5], orb[6], orb[7]}; __builtin_nontemporal_store(v, (f4*)(obase + 2 * HW_ + 4));
}

// ---------------- Fallback if ws is too small: direct gather only ----------------
__global__ __launch_bounds__(256) void
lut_affine_tanh_direct(const float* __restrict__ img,
                       const float* __restrict__ weight,
                       const float* __restrict__ bias,
                       float* __restrict__ out) {
    int t = blockIdx.x * blockDim.x + threadIdx.x;
    if (t >= N_GROUPS) return;
    int b = t >> 15;
    int p = (t & (GROUPS_PER_IMG - 1)) << 3;
    const float* base = img + (size_t)b * CHW_ + p;
    float4 r0 = *(const float4*)(base);
    float4 r1 = *(const float4*)(base + 4);
    float4 g0 = *(const float4*)(base + HW_);
    float4 g1 = *(const float4*)(base + HW_ + 4);
    float4 c0 = *(const float4*)(base + 2 * HW_);
    float4 c1 = *(const float4*)(base + 2 * HW_ + 4);
    float xr[PPT] = {r0.x, r0.y, r0.z, r0.w, r1.x, r1.y, r1.z, r1.w};
    float xg[PPT] = {g0.x, g0.y, g0.z, g0.w, g1.x, g1.y, g1.z, g1.w};
    float xb[PPT] = {c0.x, c0.y, c0.z, c0.w, c1.x, c1.y, c1.z, c1.w};
    int idx[PPT];
#pragma unroll
    for (int i = 0; i < PPT; ++i) {
        float q0 = __fmul_rn(__fadd_rn(xr[i], 1.0f), 127.5f);
        float q1 = __fmul_rn(__fadd_rn(xg[i], 1.0f), 127.5f);
        float q2 = __fmul_rn(__fadd_rn(xb[i], 1.0f), 127.5f);
        float s  = __fadd_rn(__fadd_rn(__fmul_rn(q0, 65536.0f),
                                       __fmul_rn(q1, 256.0f)), q2);
        idx[i] = (int)s;
    }
    float wv[PPT][3], bv[PPT][3];
#pragma unroll
    for (int i = 0; i < PPT; ++i) {
        const float* wp = weight + (size_t)idx[i] * 3;
        wv[i][0] = wp[0]; wv[i][1] = wp[1]; wv[i][2] = wp[2];
    }
#pragma unroll
    for (int i = 0; i < PPT; ++i) {
        const float* bp = bias + (size_t)idx[i] * 3;
        bv[i][0] = bp[0]; bv[i][1] = bp[1]; bv[i][2] = bp[2];
    }
    float orr[PPT], org[PPT], orb[PPT];
#pragma unroll
    for (int i = 0; i < PPT; ++i) {
        orr[i] = tanhf(fmaf(wv[i][0], xr[i], bv[i][0]));
        org[i] = tanhf(fmaf(wv[i][1], xg[i], bv[i][1]));
        orb[i] = tanhf(fmaf(wv[i][2], xb[i], bv[i][2]));
    }
    float* obase = out + (size_t)b * CHW_ + p;
    *(float4*)(obase)               = make_float4(orr[0], orr[1], orr[2], orr[3]);
    *(float4*)(obase + 4)           = make_float4(orr[4], orr[5], orr[6], orr[7]);
    *(float4*)(obase + HW_)         = make_float4(org[0], org[1], org[2], org[3]);
    *(float4*)(obase + HW_ + 4)     = make_float4(org[4], org[5], org[6], org[7]);
    *(float4*)(obase + 2 * HW_)     = make_float4(orb[0], orb[1], orb[2], orb[3]);
    *(float4*)(obase + 2 * HW_ + 4) = make_float4(orb[4], orb[5], orb[6], orb[7]);
}

extern "C" void kernel_launch(void* const* d_in, const int* in_sizes, int n_in,
                              void* d_out, int out_size, void* d_ws, size_t ws_size,
                              hipStream_t stream) {
    const float* img    = (const float*)d_in[0];
    const float* weight = (const float*)d_in[1];
    const float* bias   = (const float*)d_in[2];
    float* out = (float*)d_out;

    if (ws_size >= sizeof(uint32_t)) {
        uint32_t* flag = (uint32_t*)d_ws;
        flag_init_kernel<<<1, 1, 0, stream>>>(flag);
        check_uniform_kernel<<<CHK_BLOCKS, 256, 0, stream>>>(weight, bias, flag);
        apply_kernel<<<N_GROUPS / 256, 256, 0, stream>>>(img, weight, bias, flag, out);
    } else {
        lut_affine_tanh_direct<<<N_GROUPS / 256, 256, 0, stream>>>(img, weight, bias, out);
    }
}

// Round 10
// 62.075 us; speedup vs baseline: 1.7826x; 1.0175x over previous
//
#include <hip/hip_runtime.h>
#include <math.h>
#include <stdint.h>

// out[b,c,h,w] = tanh(weight[idx,c] * img[b,c,h,w] + bias[idx,c])
// idx = (int32)(q0*65536 + q1*256 + q2), q_c = (img_c + 1)*127.5  (exact fp32, no fma)
//
// R10 design. Evidence ledger:
//   R2: 4x MLP -> 0 BW change   => divergent gather throughput-capped ~3 TB/s, invariant.
//   R3-R5: >=1 random line per pixel has a ~90us floor regardless of table size.
//   R6: uniformity-check + broadcast apply = 61.8us. R8 fusion neutral (63.3).
//   R9: wave-coalesced check neutral (63.2) => check is read-BW-capped either way.
// R10 (micro, on R9 base): (1) memset node replaces the 1-thread init kernel
//   (R7's +49us regression was the nt-STRIDED check, magnitude rules out memset);
//   (2) nt on the coalesced check loads — safe now because coalesced wave
//   instructions have zero cross-instruction line overlap (R7's failure mode),
//   and 201 MB of dead streaming data shouldn't displace L2/L3.
// Floor: 201 MB check + 100 MB apply at read-BW ~= 52-57us. At >=60 => roofline.

#define HW_   (512 * 512)
#define CHW_  (3 * HW_)
#define PPT   8
#define GROUPS_PER_IMG (HW_ / PPT)
#define N_GROUPS (16 * GROUPS_PER_IMG)

#define IDX_MIN 8388607                    // min reachable idx for img in [0,1)
#define IDX_MAX 16777214                   // max reachable idx
#define CHK_BASE 8388604                   // rounded down so float base %4==0 (16B-aligned)
#define CHK_F0 ((size_t)CHK_BASE * 3)      // 25165812, %4==0
#define CHK_NV4 ((50331648UL - CHK_F0) / 4)  // 6,291,459 float4s per table
#define CHK_BLOCKS 1536
#define CHK_THREADS ((size_t)CHK_BLOCKS * 256)  // 393216, %3==0 -> fixed phase/thread

typedef float f4 __attribute__((ext_vector_type(4)));

// ---------------- Pass 1: wave-coalesced streaming uniformity check ----------------
// Verifies every row in [CHK_BASE, 16777215] equals row IDX_MIN, both tables.
// Lane i loads float4 at (t + k*CHK_THREADS): consecutive lanes -> consecutive
// 16B -> 1KB per wave instruction (16 lines). Phase t%3 is loop-invariant.
__global__ __launch_bounds__(256) void
check_uniform_kernel(const float* __restrict__ weight,
                     const float* __restrict__ bias,
                     uint32_t* __restrict__ flag) {
    size_t t = (size_t)blockIdx.x * 256 + threadIdx.x;
    int m = (int)(t % 3);

    const size_t r0 = (size_t)IDX_MIN * 3;
    float w0 = weight[r0], w1 = weight[r0 + 1], w2 = weight[r0 + 2];
    float b0 = bias[r0],   b1 = bias[r0 + 1],   b2 = bias[r0 + 2];

    // expected float4 for this thread's phase (component c has row-component (m+c)%3)
    f4 ew = (m == 0) ? (f4){w0, w1, w2, w0}
          : (m == 1) ? (f4){w1, w2, w0, w1}
                     : (f4){w2, w0, w1, w2};
    f4 eb = (m == 0) ? (f4){b0, b1, b2, b0}
          : (m == 1) ? (f4){b1, b2, b0, b1}
                     : (f4){b2, b0, b1, b2};

    const f4* pw = (const f4*)(weight + CHK_F0);
    const f4* pb = (const f4*)(bias + CHK_F0);

    bool mm = false;
    for (size_t i = t; i < CHK_NV4; i += CHK_THREADS) {
        f4 a = __builtin_nontemporal_load(pw + i);
        f4 c = __builtin_nontemporal_load(pb + i);
        mm |= (a.x != ew.x) | (a.y != ew.y) | (a.z != ew.z) | (a.w != ew.w);
        mm |= (c.x != eb.x) | (c.y != eb.y) | (c.z != eb.z) | (c.w != eb.w);
    }

    if (__any(mm) && (threadIdx.x & 63) == 0)   // one atomic per wave, mismatch only
        atomicOr(flag, 1u);
}

// ---------------- Pass 2: apply (R6-proven, unchanged) ----------------
// flag==0 (uniform LUT): pure streaming tanh(w*x+b), zero gathers.
// flag!=0: direct 2-table gather per pixel (always correct).
// Either way, per-pixel out-of-verified-range idx falls back to a direct gather.
__global__ __launch_bounds__(256) void
apply_kernel(const float* __restrict__ img,
             const float* __restrict__ weight,
             const float* __restrict__ bias,
             const uint32_t* __restrict__ flag,
             float* __restrict__ out) {
    int t = blockIdx.x * blockDim.x + threadIdx.x;
    if (t >= N_GROUPS) return;

    int b = t >> 15;
    int p = (t & (GROUPS_PER_IMG - 1)) << 3;

    const float* base = img + (size_t)b * CHW_ + p;
    f4 r0 = __builtin_nontemporal_load((const f4*)(base));
    f4 r1 = __builtin_nontemporal_load((const f4*)(base + 4));
    f4 g0 = __builtin_nontemporal_load((const f4*)(base + HW_));
    f4 g1 = __builtin_nontemporal_load((const f4*)(base + HW_ + 4));
    f4 c0 = __builtin_nontemporal_load((const f4*)(base + 2 * HW_));
    f4 c1 = __builtin_nontemporal_load((const f4*)(base + 2 * HW_ + 4));

    float xr[PPT] = {r0.x, r0.y, r0.z, r0.w, r1.x, r1.y, r1.z, r1.w};
    float xg[PPT] = {g0.x, g0.y, g0.z, g0.w, g1.x, g1.y, g1.z, g1.w};
    float xb[PPT] = {c0.x, c0.y, c0.z, c0.w, c1.x, c1.y, c1.z, c1.w};

    // Exact-fp32 index math (bit-matches numpy; never fma-contracted)
    int idx[PPT];
#pragma unroll
    for (int i = 0; i < PPT; ++i) {
        float q0 = __fmul_rn(__fadd_rn(xr[i], 1.0f), 127.5f);
        float q1 = __fmul_rn(__fadd_rn(xg[i], 1.0f), 127.5f);
        float q2 = __fmul_rn(__fadd_rn(xb[i], 1.0f), 127.5f);
        float s  = __fadd_rn(__fadd_rn(__fmul_rn(q0, 65536.0f),
                                       __fmul_rn(q1, 256.0f)),
                             q2);
        idx[i] = (int)s;
    }

    float wv[PPT][3], bv[PPT][3];
    bool uni = (flag[0] == 0u);   // grid-uniform scalar branch

    if (uni) {
        const size_t rr = (size_t)IDX_MIN * 3;
        float uw0 = weight[rr], uw1 = weight[rr + 1], uw2 = weight[rr + 2];
        float ub0 = bias[rr],   ub1 = bias[rr + 1],   ub2 = bias[rr + 2];
#pragma unroll
        for (int i = 0; i < PPT; ++i) {
            wv[i][0] = uw0; wv[i][1] = uw1; wv[i][2] = uw2;
            bv[i][0] = ub0; bv[i][1] = ub1; bv[i][2] = ub2;
        }
        // Safety: idx outside the verified range -> direct gather (never taken
        // for img in [0,1); wave-uniformly false -> s_cbranch_execz skips)
#pragma unroll
        for (int i = 0; i < PPT; ++i) {
            if ((unsigned)(idx[i] - IDX_MIN) > (unsigned)(IDX_MAX - IDX_MIN)) {
                const float* wp = weight + (size_t)idx[i] * 3;
                const float* bp = bias   + (size_t)idx[i] * 3;
                wv[i][0] = wp[0]; wv[i][1] = wp[1]; wv[i][2] = wp[2];
                bv[i][0] = bp[0]; bv[i][1] = bp[1]; bv[i][2] = bp[2];
            }
        }
    } else {
        // Non-uniform LUT: direct 2-table gather per pixel (correct, slower)
#pragma unroll
        for (int i = 0; i < PPT; ++i) {
            const float* wp = weight + (size_t)idx[i] * 3;
            wv[i][0] = wp[0]; wv[i][1] = wp[1]; wv[i][2] = wp[2];
        }
#pragma unroll
        for (int i = 0; i < PPT; ++i) {
            const float* bp = bias + (size_t)idx[i] * 3;
            bv[i][0] = bp[0]; bv[i][1] = bp[1]; bv[i][2] = bp[2];
        }
    }

    float orr[PPT], org[PPT], orb[PPT];
#pragma unroll
    for (int i = 0; i < PPT; ++i) {
        orr[i] = tanhf(fmaf(wv[i][0], xr[i], bv[i][0]));
        org[i] = tanhf(fmaf(wv[i][1], xg[i], bv[i][1]));
        orb[i] = tanhf(fmaf(wv[i][2], xb[i], bv[i][2]));
    }

    float* obase = out + (size_t)b * CHW_ + p;
    f4 v;
    v = (f4){orr[0], orr[1], orr[2], orr[3]}; __builtin_nontemporal_store(v, (f4*)(obase));
    v = (f4){orr[4], orr[5], orr[6], orr[7]}; __builtin_nontemporal_store(v, (f4*)(obase + 4));
    v = (f4){org[0], org[1], org[2], org[3]}; __builtin_nontemporal_store(v, (f4*)(obase + HW_));
    v = (f4){org[4], org[5], org[6], org[7]}; __builtin_nontemporal_store(v, (f4*)(obase + HW_ + 4));
    v = (f4){orb[0], orb[1], orb[2], orb[3]}; __builtin_nontemporal_store(v, (f4*)(obase + 2 * HW_));
    v = (f4){orb[4], orb[5], orb[6], orb[7]}; __builtin_nontemporal_store(v, (f4*)(obase + 2 * HW_ + 4));
}

// ---------------- Fallback if ws is too small: direct gather only ----------------
__global__ __launch_bounds__(256) void
lut_affine_tanh_direct(const float* __restrict__ img,
                       const float* __restrict__ weight,
                       const float* __restrict__ bias,
                       float* __restrict__ out) {
    int t = blockIdx.x * blockDim.x + threadIdx.x;
    if (t >= N_GROUPS) return;
    int b = t >> 15;
    int p = (t & (GROUPS_PER_IMG - 1)) << 3;
    const float* base = img + (size_t)b * CHW_ + p;
    float4 r0 = *(const float4*)(base);
    float4 r1 = *(const float4*)(base + 4);
    float4 g0 = *(const float4*)(base + HW_);
    float4 g1 = *(const float4*)(base + HW_ + 4);
    float4 c0 = *(const float4*)(base + 2 * HW_);
    float4 c1 = *(const float4*)(base + 2 * HW_ + 4);
    float xr[PPT] = {r0.x, r0.y, r0.z, r0.w, r1.x, r1.y, r1.z, r1.w};
    float xg[PPT] = {g0.x, g0.y, g0.z, g0.w, g1.x, g1.y, g1.z, g1.w};
    float xb[PPT] = {c0.x, c0.y, c0.z, c0.w, c1.x, c1.y, c1.z, c1.w};
    int idx[PPT];
#pragma unroll
    for (int i = 0; i < PPT; ++i) {
        float q0 = __fmul_rn(__fadd_rn(xr[i], 1.0f), 127.5f);
        float q1 = __fmul_rn(__fadd_rn(xg[i], 1.0f), 127.5f);
        float q2 = __fmul_rn(__fadd_rn(xb[i], 1.0f), 127.5f);
        float s  = __fadd_rn(__fadd_rn(__fmul_rn(q0, 65536.0f),
                                       __fmul_rn(q1, 256.0f)), q2);
        idx[i] = (int)s;
    }
    float wv[PPT][3], bv[PPT][3];
#pragma unroll
    for (int i = 0; i < PPT; ++i) {
        const float* wp = weight + (size_t)idx[i] * 3;
        wv[i][0] = wp[0]; wv[i][1] = wp[1]; wv[i][2] = wp[2];
    }
#pragma unroll
    for (int i = 0; i < PPT; ++i) {
        const float* bp = bias + (size_t)idx[i] * 3;
        bv[i][0] = bp[0]; bv[i][1] = bp[1]; bv[i][2] = bp[2];
    }
    float orr[PPT], org[PPT], orb[PPT];
#pragma unroll
    for (int i = 0; i < PPT; ++i) {
        orr[i] = tanhf(fmaf(wv[i][0], xr[i], bv[i][0]));
        org[i] = tanhf(fmaf(wv[i][1], xg[i], bv[i][1]));
        orb[i] = tanhf(fmaf(wv[i][2], xb[i], bv[i][2]));
    }
    float* obase = out + (size_t)b * CHW_ + p;
    *(float4*)(obase)               = make_float4(orr[0], orr[1], orr[2], orr[3]);
    *(float4*)(obase + 4)           = make_float4(orr[4], orr[5], orr[6], orr[7]);
    *(float4*)(obase + HW_)         = make_float4(org[0], org[1], org[2], org[3]);
    *(float4*)(obase + HW_ + 4)     = make_float4(org[4], org[5], org[6], org[7]);
    *(float4*)(obase + 2 * HW_)     = make_float4(orb[0], orb[1], orb[2], orb[3]);
    *(float4*)(obase + 2 * HW_ + 4) = make_float4(orb[4], orb[5], orb[6], orb[7]);
}

extern "C" void kernel_launch(void* const* d_in, const int* in_sizes, int n_in,
                              void* d_out, int out_size, void* d_ws, size_t ws_size,
                              hipStream_t stream) {
    const float* img    = (const float*)d_in[0];
    const float* weight = (const float*)d_in[1];
    const float* bias   = (const float*)d_in[2];
    float* out = (float*)d_out;

    if (ws_size >= sizeof(uint32_t)) {
        uint32_t* flag = (uint32_t*)d_ws;
        hipMemsetAsync(flag, 0, sizeof(uint32_t), stream);  // graph-legal memset node
        check_uniform_kernel<<<CHK_BLOCKS, 256, 0, stream>>>(weight, bias, flag);
        apply_kernel<<<N_GROUPS / 256, 256, 0, stream>>>(img, weight, bias, flag, out);
    } else {
        lut_affine_tanh_direct<<<N_GROUPS / 256, 256, 0, stream>>>(img, weight, bias, out);
    }
}